// Round 9
// baseline (537.716 us; speedup 1.0000x reference)
//
#include <hip/hip_runtime.h>
#include <hip/hip_fp16.h>
#include <stdint.h>

#define HH 256
#define WW 1216
#define BB 2
#define CC 64
#define IPIX (HH*WW)
#define NPIX (BB*IPIX)
// padded aff planes: left pad 32 (64B-aligned rows), right pad, 3-row halo top/bottom
#define PW 1280
#define PH 262
#define PPIX (PH*PW)               // 335360
#define PLSTRIDE (BB*PPIX)         // 670720
#define XOFF 32

typedef __attribute__((ext_vector_type(8))) __bf16 bf16x8;
typedef __attribute__((ext_vector_type(4))) __bf16 bf16x4;
typedef __attribute__((ext_vector_type(4))) float floatx4;

__device__ __forceinline__ float sigm(float x) { return 1.f / (1.f + __expf(-x)); }

// layer order: aff7(24), aff5(16), aff3(8), att7(6), att5(6), att3(6), att1(6), mask(6)
constexpr int LSTART_H[9] = {0,24,40,48,54,60,66,72,78};

// 7x7 tap -> aff plane index (-1 = center, uses g1 with no aff factor)
constexpr int PLANE[49] = {
  0, 1, 2, 3, 4, 5, 6,
  7,24,25,26,27,28, 8,
  9,29,40,41,42,30,10,
 11,31,43,-1,44,32,12,
 13,33,45,46,47,34,14,
 15,35,36,37,38,39,16,
 17,18,19,20,21,22,23};
// 7x7 tap -> kernel class: 0='7', 1='5', 2='3', 3='1'
constexpr int KCLS[49] = {
 0,0,0,0,0,0,0,
 0,1,1,1,1,1,0,
 0,1,2,2,2,1,0,
 0,1,2,3,2,1,0,
 0,1,2,2,2,1,0,
 0,1,1,1,1,1,0,
 0,0,0,0,0,0,0};
// the 48 non-center taps in order
constexpr int TAPNC[48] = {
  0,1,2,3,4,5,6,7,8,9,10,11,12,13,14,15,16,17,18,19,20,21,22,23,
  25,26,27,28,29,30,31,32,33,34,35,36,37,38,39,40,41,42,43,44,45,46,47,48};

struct WPtrs {
    const float* w[8];
    const float* s[8];
    const float* b[8];
};

// ---------------- K0: pack weights into MFMA A-fragment layout (bf16) ----------------
__global__ void k_pack(WPtrs wp, __bf16* __restrict__ wpk,
                       float* __restrict__ s_all, float* __restrict__ b_all) {
    int idx = blockIdx.x * blockDim.x + threadIdx.x;
    if (idx < 18 * 5 * 64) {
        int kk = idx / (5 * 64);
        int r = idx - kk * 5 * 64;
        int t = r >> 6, lane = r & 63;
        int m = t * 16 + (lane & 15);
        int L = 0, o = 0;
        bool valid_m = (m < 78);
        if (valid_m) {
            for (int i = 0; i < 8; i++) if (m >= LSTART_H[i]) { L = i; o = m - LSTART_H[i]; }
        }
        __bf16 vals[8];
        for (int j = 0; j < 8; j++) {
            int k = kk * 32 + ((lane >> 4) * 8) + j;
            int tap = k >> 6, c = k & 63;
            float w = valid_m ? wp.w[L][(o * 64 + c) * 9 + tap] : 0.f;
            vals[j] = (__bf16)w;
        }
        for (int j = 0; j < 8; j++) wpk[(size_t)idx * 8 + j] = vals[j];
    }
    if (idx < 80) {
        int m = idx;
        float sv = 0.f, bv = 0.f;
        if (m < 78) {
            int L = 0, o = 0;
            for (int i = 0; i < 8; i++) if (m >= LSTART_H[i]) { L = i; o = m - LSTART_H[i]; }
            sv = wp.s[L][o]; bv = wp.b[L][o];
        }
        s_all[m] = sv; b_all[m] = bv;
    }
}

// ---------------- K0b: zero the pad borders of aff (48 padded planes) ----------------
__global__ void k_zero_pad(__bf16* __restrict__ aff_p) {
    const int perPB = 6 * PW + 256 * 16;   // 11776
    int idx = blockIdx.x * blockDim.x + threadIdx.x;
    int total = 48 * BB * perPB;
    if (idx >= total) return;
    int pbi = idx / perPB;
    int e = idx - pbi * perPB;
    int plane = pbi >> 1, b = pbi & 1;
    int r, c;
    if (e < 6 * PW) {
        int rr = e / PW; c = e - rr * PW;
        r = (rr < 3) ? rr : (259 + rr - 3);
    } else {
        int j = e - 6 * PW;
        r = 3 + (j >> 4);
        int c16 = j & 15;
        c = (c16 < 8) ? (24 + c16) : (1248 + c16 - 8);
    }
    aff_p[(size_t)plane * PLSTRIDE + (size_t)b * PPIX + r * PW + c] = (__bf16)0.f;
}

// ---------------- K0c: feature fp32 NCHW -> bf16 (b,y,x,[c]) channel-packed ----------------
__global__ __launch_bounds__(256) void k_cvt(const float* __restrict__ feat,
                                             __bf16* __restrict__ fpk) {
    const int x = blockIdx.x * 64 + (threadIdx.x & 63);
    const int half = threadIdx.x >> 6;            // 0..3
    const int y = blockIdx.y, b = blockIdx.z;
    const float* fb = feat + (size_t)b * CC * IPIX + (size_t)y * WW + x;
    __bf16* op = fpk + ((size_t)(b * IPIX + y * WW + x) << 6);
#pragma unroll
    for (int h = 0; h < 2; h++) {
        const int cg = half + h * 4;              // channel group of 8
        bf16x8 pk;
#pragma unroll
        for (int j = 0; j < 8; j++) pk[j] = (__bf16)fb[(size_t)(cg * 8 + j) * IPIX];
        *(bf16x8*)(op + cg * 8) = pk;
    }
}

// ---------------- K1: conv implicit GEMM + fused epilogue (stats, sigmoid, r/gd) ----------------
// Block: 256 thr = 4 waves; pixel tile 32 wide x 4 high; wave w = row w, 2 N-frags of 16.
// LDS: sh feature tile 29376 B (reused: transpose 21120 B + stats 3072 B) + wlds 10240 B.
__global__ __launch_bounds__(256, 4) void k_conv(const __bf16* __restrict__ fpk,
        const float* __restrict__ d00, const float* __restrict__ d0,
        const __bf16* __restrict__ wpk,
        const float* __restrict__ s_all, const float* __restrict__ b_all,
        __bf16* __restrict__ aff_p, __bf16* __restrict__ maskp,
        float* __restrict__ rgd) {
    __shared__ __bf16 sh[6 * 34 * 72];
    __shared__ __bf16 wlds[2 * 2560];
    const int tid = threadIdx.x;
    // XCD-aware swizzle: contiguous y-slabs per XCD for halo L2 locality
    int flat = blockIdx.x + 38 * (blockIdx.y + 64 * blockIdx.z);
    int nf = (flat & 7) * 608 + (flat >> 3);
    int bx = nf % 38; int r2 = nf / 38;
    const int x0 = bx * 32, y0 = (r2 & 63) * 4, b = r2 >> 6;

    // prefetch weight panel 0
    {
        bf16x8 w0 = *(const bf16x8*)(wpk + (size_t)tid * 8);
        *(bf16x8*)(wlds + tid * 8) = w0;
        if (tid < 64) {
            bf16x8 w1 = *(const bf16x8*)(wpk + 2048 + (size_t)tid * 8);
            *(bf16x8*)(wlds + 2048 + tid * 8) = w1;
        }
    }
    // stage feature tile from packed bf16: fully coalesced dwordx4 + ds_write_b128
    for (int idx = tid; idx < 204 * 8; idx += 256) {
        int cg = idx & 7, pos = idx >> 3;
        int row = pos / 34, x = pos - row * 34;
        int gy = y0 + row - 1, gx = x0 + x - 1;
        bf16x8 pk;
#pragma unroll
        for (int j = 0; j < 8; j++) pk[j] = (__bf16)0.f;
        if (gy >= 0 && gy < HH && gx >= 0 && gx < WW)
            pk = *(const bf16x8*)(fpk + ((size_t)(b * IPIX + gy * WW + gx) << 6) + cg * 8);
        *(bf16x8*)(sh + pos * 72 + cg * 8) = pk;
    }
    __syncthreads();

    const int wave = tid >> 6, lane = tid & 63;
    const int n = lane & 15, g = lane >> 4;

    floatx4 acc[5][2];
#pragma unroll
    for (int t = 0; t < 5; t++)
#pragma unroll
        for (int q = 0; q < 2; q++) acc[t][q] = (floatx4)(0.f);

#pragma unroll
    for (int kk = 0; kk < 18; kk++) {
        bf16x8 wt0, wt1;
        if (kk < 17) {
            wt0 = *(const bf16x8*)(wpk + (size_t)(kk + 1) * 2560 + tid * 8);
            if (tid < 64) wt1 = *(const bf16x8*)(wpk + (size_t)(kk + 1) * 2560 + 2048 + tid * 8);
        }
        const int tap = kk >> 1;
        const int dy = tap / 3 - 1, dx = tap % 3 - 1;
        const int c0 = (kk & 1) * 32 + g * 8;
        bf16x8 bfr[2];
        const int rowb = wave + 1 + dy;
        const int colb = 1 + dx + n;
#pragma unroll
        for (int q = 0; q < 2; q++)
            bfr[q] = *(const bf16x8*)(sh + ((rowb * 34) + colb + q * 16) * 72 + c0);
        bf16x8 afr[5];
        const __bf16* wb = wlds + (kk & 1) * 2560 + lane * 8;
#pragma unroll
        for (int t = 0; t < 5; t++) afr[t] = *(const bf16x8*)(wb + t * 512);
#pragma unroll
        for (int t = 0; t < 5; t++)
#pragma unroll
            for (int q = 0; q < 2; q++)
                acc[t][q] = __builtin_amdgcn_mfma_f32_16x16x32_bf16(afr[t], bfr[q], acc[t][q], 0, 0, 0);
        if (kk < 17) {
            *(bf16x8*)(wlds + ((kk + 1) & 1) * 2560 + tid * 8) = wt0;
            if (tid < 64) *(bf16x8*)(wlds + ((kk + 1) & 1) * 2560 + 2048 + tid * 8) = wt1;
        }
        __syncthreads();
    }

    // phase 1: scale/bias + stats; bf16 results into LDS sh[m*132 + wave*32 + n + 16q]
    float p7[2] = {0,0}, t7[2] = {0,0};
    float p5[2] = {0,0}, t5[2] = {0,0};
    float p3[2] = {0,0}, t3[2] = {0,0};

#pragma unroll
    for (int t = 0; t < 5; t++) {
        const floatx4 sv = *(const floatx4*)(s_all + t * 16 + 4 * g);
        const floatx4 bv = *(const floatx4*)(b_all + t * 16 + 4 * g);
#pragma unroll
        for (int q = 0; q < 2; q++) {
#pragma unroll
            for (int reg = 0; reg < 4; reg++) {
                const int m = t * 16 + 4 * g + reg;
                const float v = fmaf(acc[t][q][reg], sv[reg], bv[reg]);
                if (m < 24)                { p7[q] += fabsf(v); t7[q] += v; }
                else if (m < 40)           { p5[q] += fabsf(v); t5[q] += v; }
                else if (m < 48)           { p3[q] += fabsf(v); t3[q] += v; }
                const float outv = (m < 48) ? v : sigm(v);
                sh[m * 132 + wave * 32 + n + q * 16] = (__bf16)outv;
            }
        }
    }
#pragma unroll
    for (int q = 0; q < 2; q++) {
        p7[q] += __shfl_xor(p7[q], 16); p7[q] += __shfl_xor(p7[q], 32);
        t7[q] += __shfl_xor(t7[q], 16); t7[q] += __shfl_xor(t7[q], 32);
        p5[q] += __shfl_xor(p5[q], 16); p5[q] += __shfl_xor(p5[q], 32);
        t5[q] += __shfl_xor(t5[q], 16); t5[q] += __shfl_xor(t5[q], 32);
        p3[q] += __shfl_xor(p3[q], 16); p3[q] += __shfl_xor(p3[q], 32);
        t3[q] += __shfl_xor(t3[q], 16); t3[q] += __shfl_xor(t3[q], 32);
    }
    // stats into spare LDS (bytes 21120..24192, after the 80*132 bf16 transpose area)
    float* stl = (float*)(sh + 10560);   // [128 px][6]
    if (g == 0) {
#pragma unroll
        for (int q = 0; q < 2; q++) {
            const int pxq = wave * 32 + n + q * 16;
            stl[pxq * 6 + 0] = p7[q]; stl[pxq * 6 + 1] = p5[q]; stl[pxq * 6 + 2] = p3[q];
            stl[pxq * 6 + 3] = t7[q]; stl[pxq * 6 + 4] = t5[q]; stl[pxq * 6 + 5] = t3[q];
        }
    }
    __syncthreads();

    // phase 2: transpose-read, coalesced stores; fused r/gd computation (was k_rg)
    const int px = tid & 127;
    const int grp = tid >> 7;
    const int prow = px >> 5, pcol = px & 31;
    const size_t ppx = (size_t)b * PPIX + (y0 + prow + 3) * PW + (x0 + pcol + XOFF);
    const int pix = b * IPIX + (y0 + prow) * WW + x0 + pcol;
#pragma unroll
    for (int m = 0; m < 48; m += 2) {
        aff_p[(size_t)(m + grp) * PLSTRIDE + ppx] = sh[(m + grp) * 132 + px];
    }
    const float S7 = stl[px * 6 + 0], S5 = stl[px * 6 + 1], S3 = stl[px * 6 + 2];
    const float T7 = stl[px * 6 + 3], T5 = stl[px * 6 + 4], T3 = stl[px * 6 + 5];
    const float d0v = d0[pix];
    const float valid = (d00[pix] > 0.f) ? 1.f : 0.f;
#pragma unroll
    for (int j = 0; j < 6; j += 2) {
        const int it = j + grp;
        float a7 = (float)sh[(48 + it) * 132 + px];
        float a5 = (float)sh[(54 + it) * 132 + px];
        float a3 = (float)sh[(60 + it) * 132 + px];
        float a1 = (float)sh[(66 + it) * 132 + px];
        float denom = a7 * S7 + a5 * S5 + a3 * S3 + a1;   // > 0: a1 = sigmoid > 0
        float inv = 1.f / denom;
        float r7 = a7 * inv, r5 = a5 * inv, r3 = a3 * inv, r1 = a1 * inv;
        float g0 = 1.f - (r7 * T7 + r5 * T5 + r3 * T3 + r1);
        union { float f; _Float16 h[2]; } w0, w1;
        w0.h[0] = (_Float16)r7; w0.h[1] = (_Float16)r5;
        w1.h[0] = (_Float16)r3; w1.h[1] = (_Float16)r1;
        floatx4 rec = {w0.f, w1.f, g0 * d0v, 0.f};
        *(floatx4*)(rgd + ((size_t)it * NPIX + pix) * 4) = rec;
        maskp[(size_t)it * NPIX + pix] = (__bf16)((float)sh[(72 + it) * 132 + px] * valid);
    }
}

// ---------------- K3 (per iter): LDS p-planes + batched 49-tap gather ----------------
// Tile 32x16, 512 threads (8 waves); halo 38x22 (amplification 1.63x).
__global__ __launch_bounds__(512) void k_iter(const float* __restrict__ rgd,
        const float* __restrict__ dt,
        const __bf16* __restrict__ aff_p, const __bf16* __restrict__ maskp,
        const float* __restrict__ d00,
        float* __restrict__ dtn, int it) {
    __shared__ float sp[5][22 * 38];
    const int tid = threadIdx.x;
    const int tx = tid & 31, ty = tid >> 5;
    int flat = blockIdx.x + 38 * (blockIdx.y + 16 * blockIdx.z);
    int nf = (flat & 7) * 152 + (flat >> 3);
    int bx = nf % 38; int r2 = nf / 38;
    const int x0 = bx * 32, y0 = (r2 & 15) * 16, b = r2 >> 4;
    const int ib = b * IPIX;

    for (int idx = tid; idx < 22 * 38; idx += 512) {
        int r = idx / 38, col = idx - r * 38;
        int gy = y0 + r - 3, gx = x0 + col - 3;
        float v7 = 0.f, v5 = 0.f, v3 = 0.f, v1 = 0.f, vb = 0.f;
        if (gy >= 0 && gy < HH && gx >= 0 && gx < WW) {
            int q = ib + gy * WW + gx;
            const floatx4 v = *(const floatx4*)(rgd + ((size_t)it * NPIX + q) * 4);
            union { float f; _Float16 h[2]; } u0, u1;
            u0.f = v[0]; u1.f = v[1];
            float dtv = dt[q];
            v7 = (float)u0.h[0] * dtv; v5 = (float)u0.h[1] * dtv;
            v3 = (float)u1.h[0] * dtv; v1 = (float)u1.h[1] * dtv;
            vb = v[2];
        }
        sp[0][idx] = v7; sp[1][idx] = v5; sp[2][idx] = v3; sp[3][idx] = v1; sp[4][idx] = vb;
    }
    __syncthreads();

    const int y = y0 + ty, x = x0 + tx;
    const int pix = ib + y * WW + x;
    const __bf16* ap = aff_p + (size_t)b * PPIX + (y + 3) * PW + (x + XOFF);

    // center + base
    float acc0 = sp[4][(ty + 3) * 38 + (tx + 3)] + sp[3][(ty + 3) * 38 + (tx + 3)];
    float acc1 = 0.f, acc2 = 0.f, acc3 = 0.f;
    // 6 batches of 8: 8 aff loads in flight per waitcnt
#pragma unroll
    for (int bt = 0; bt < 6; bt++) {
        float a8[8];
#pragma unroll
        for (int j = 0; j < 8; j++) {
            const int t = TAPNC[bt * 8 + j];
            const int dy = 3 - t / 7, dx = 3 - (t % 7);
            a8[j] = (float)ap[(ptrdiff_t)PLANE[t] * PLSTRIDE + dy * PW + dx];
        }
#pragma unroll
        for (int j = 0; j < 8; j++) {
            const int t = TAPNC[bt * 8 + j];
            const int dy = 3 - t / 7, dx = 3 - (t % 7);
            const float pv = sp[KCLS[t]][(ty + dy + 3) * 38 + (tx + dx + 3)];
            switch (j & 3) {
                case 0: acc0 = fmaf(a8[j], pv, acc0); break;
                case 1: acc1 = fmaf(a8[j], pv, acc1); break;
                case 2: acc2 = fmaf(a8[j], pv, acc2); break;
                default: acc3 = fmaf(a8[j], pv, acc3); break;
            }
        }
    }
    float acc = (acc0 + acc1) + (acc2 + acc3);
    float m = (float)maskp[(size_t)it * NPIX + pix];
    float dtv = m * d00[pix] + (1.f - m) * acc;
    dtn[pix] = dtv;
}

// ---------------- launch ----------------
extern "C" void kernel_launch(void* const* d_in, const int* in_sizes, int n_in,
                              void* d_out, int out_size, void* d_ws, size_t ws_size,
                              hipStream_t stream) {
    const float* feat = (const float*)d_in[0];
    const float* d0   = (const float*)d_in[1];
    const float* d00  = (const float*)d_in[2];
    WPtrs wp;
    for (int l = 0; l < 8; l++) {
        wp.w[l] = (const float*)d_in[3 + 3 * l];
        wp.s[l] = (const float*)d_in[4 + 3 * l];
        wp.b[l] = (const float*)d_in[5 + 3 * l];
    }
    __bf16*   wsb   = (__bf16*)d_ws;
    __bf16*   aff_p = wsb;                                   // 48 padded planes bf16 (64.4 MB)
    __bf16*   msk_b = aff_p + (size_t)48 * PLSTRIDE;         // 6 planes bf16 (7.5 MB)
    float*    rgd   = (float*)(msk_b + (size_t)6 * NPIX);    // 6*NPIX*16 B (59.8 MB)
    float*    dtA   = rgd + (size_t)24 * NPIX;               // 1 fp32 plane (ping)
    __bf16*   wpk   = (__bf16*)(dtA + (size_t)NPIX);         // 92160 B packed weights
    float*    s_all = (float*)(wpk + 18 * 5 * 64 * 8);
    float*    b_all = s_all + 80;
    __bf16*   fpk   = (__bf16*)(b_all + 80);                 // 64*NPIX bf16 (79.7 MB)
    float*    dtB   = (float*)d_out;                         // pong (overwritten before reads)

    hipLaunchKernelGGL(k_pack, dim3(23), dim3(256), 0, stream, wp, wpk, s_all, b_all);
    hipLaunchKernelGGL(k_zero_pad, dim3((48 * BB * (6 * PW + 256 * 16) + 255) / 256), dim3(256),
                       0, stream, aff_p);
    hipLaunchKernelGGL(k_cvt, dim3(WW / 64, HH, BB), dim3(256), 0, stream, feat, fpk);
    hipLaunchKernelGGL(k_conv, dim3(38, 64, 2), dim3(256), 0, stream,
                       fpk, d00, d0, wpk, s_all, b_all, aff_p, msk_b, rgd);
    const float* cur = d0;
    for (int it = 0; it < 6; ++it) {
        float* nxt = (it & 1) ? dtB : dtA;
        if (it == 5) nxt = dtB;
        hipLaunchKernelGGL(k_iter, dim3(38, 16, 2), dim3(512), 0, stream,
                           rgd, cur, aff_p, msk_b, d00, nxt, it);
        cur = nxt;
    }
}